// Round 13
// baseline (90.420 us; speedup 1.0000x reference)
//
#include <hip/hip_runtime.h>

#define L2E 1.44269504088896340736f   // log2(e)
#define LN2 0.69314718055994530942f

// Raw HW transcendentals: v_exp_f32 = 2^x, v_log_f32 = log2(x).
#define EXP2F(x) __builtin_amdgcn_exp2f(x)
#define LOG2F(x) __builtin_amdgcn_logf(x)

// Probability-domain soft-min DP; one wave per batch; lane t owns rows
// 4t..4t+3.  w = 2^(sigma-E), E = D*log2e;  w_new = g*(wa+wb+wc),
// g = 2^(-C*log2e).  Round-12 post-mortem: the 64-line divergent gather
// (rows 1KB apart) thrashes L1 (2 waves x 16KB footprint = 32KB) and
// saturates MSHRs -> ~200cy/step memory serialization.  Fix: stage C
// through LDS with COALESCED 1KB wave-loads (16 rows x 64B, 16 lines/instr,
// single-touch streaming), swizzle folded into the GLOBAL gather so
// ds_writes are linear and ds_reads bank-spread.  Single wave => no
// barriers; write->read margins >= 11 steps by schedule construction.
//
// LDS: float4 lds4[4096] = [w&3][g][64 chunks] (64KB).  Window (g,w) holds
// rows 16g..16g+15, cols 16w..16w+15.  Chunk l of slot (g,w) holds
// row 16g+q(l), quad col 16w+4*mm(l), q(l)=(l>>2)^(l>>5),
// mm(l)=(l&3)^((q>>1)&3)^(g&3)  [self-inverse; read side recomputes].
// Schedule: pair (G=2i, 2i+1) with w=sigma-G loaded at body slot i (i<8),
// ds_written at slot i+4; sigma = kb/16 + 2.  Deadline(g,w) = 16(g+w)-4.
// Consumption: rotation at step kk (P=kk&3) converts RQ (LDS quad read 2
// steps earlier, covering cols [u,u+4), u = kk+4-r) into nP; cP<-nP.
// ok-mask (u==clamp(u)) zeroes junk (u<0 pre-start / u>252 past-end) and
// protects against garbage LDS bits.  Renorm every 64 diags (exact 2^-e,
// sig -= e).  w1/w2 buffers alternate by kk parity (no shift movs).

template <int I> __device__ __forceinline__ float comp(const float4& v) {
    if constexpr (I == 0) return v.x;
    else if constexpr (I == 1) return v.y;
    else if constexpr (I == 2) return v.z;
    else return v.w;
}

__device__ __forceinline__ float4 g4f(const float4& v) {
    float4 r;
    r.x = EXP2F(v.x * -L2E); r.y = EXP2F(v.y * -L2E);
    r.z = EXP2F(v.z * -L2E); r.w = EXP2F(v.w * -L2E);
    return r;
}

// LDS read of the quad covering cols [ucl, ucl+4) of phase-P row.
template <int P>
__device__ __forceinline__ float4 lds_rd(const float4* lds4, int kkq,
    int rr0,int rr1,int rr2,int rr3, int AA0,int AA1,int AA2,int AA3,
    int qq0,int qq1,int qq2,int qq3)
{
    const int rr = (P==0)?rr0:(P==1)?rr1:(P==2)?rr2:rr3;
    const int AA = (P==0)?AA0:(P==1)?AA1:(P==2)?AA2:AA3;
    const int qq = (P==0)?qq0:(P==1)?qq1:(P==2)?qq2:qq3;
    int u = kkq + 4 - rr;
    int ucl = u < 0 ? 0 : (u > 252 ? 252 : u);
    int cidx = AA + (((ucl >> 4) & 3) << 10) + ((((ucl >> 2) & 3) ^ qq));
    return lds4[cidx];
}

template <int G>
__device__ __forceinline__ void stage_load(int sigma, const float* __restrict__ Cb,
    int v0,int v1,int v2,int v3, float4& L)
{
    int w = sigma - G;
    if (0 <= w && w < 16) {
        constexpr int p = G & 3;
        const int vo = (p==0)?v0:(p==1)?v1:(p==2)?v2:v3;
        L = *(const float4*)(Cb + 4096*G + 16*w + vo);
    }
}

template <int G>
__device__ __forceinline__ void stage_write(int sigma, float4* lds4, int t, const float4& L)
{
    int w = sigma - G;
    if (0 <= w && w < 16)
        lds4[((w & 3) * 16 + G) * 64 + t] = L;
}

template <int P>
__device__ __forceinline__ void stepf(int kk, int t, float4* lds4,
    int rr0,int rr1,int rr2,int rr3, int AA0,int AA1,int AA2,int AA3,
    int qq0,int qq1,int qq2,int qq3,
    float4& RQ,
    float4& c0,float4& c1,float4& c2,float4& c3,
    float4& n0,float4& n1,float4& n2,float4& n3,
    float& w10,float& w11,float& w12,float& w13,   // prev diag (in)
    float& w20,float& w21,float& w22,float& w23,   // prev-prev (in) + OUT
    float& pd1, float& pd2)
{
    const int rr = (P==0)?rr0:(P==1)?rr1:(P==2)?rr2:rr3;
    // convert RQ (read 2 steps ago, covers cols [u, u+4) of row rr)
    int u = kk + 4 - rr;
    int ucl = u < 0 ? 0 : (u > 252 ? 252 : u);
    bool ok = (u == ucl);
    float4 gq;
    gq.x = ok ? EXP2F(RQ.x * -L2E) : 0.0f;
    gq.y = ok ? EXP2F(RQ.y * -L2E) : 0.0f;
    gq.z = ok ? EXP2F(RQ.z * -L2E) : 0.0f;
    gq.w = ok ? EXP2F(RQ.w * -L2E) : 0.0f;
    float4& cP = (P==0)?c0:(P==1)?c1:(P==2)?c2:c3;
    float4& nP = (P==0)?n0:(P==1)?n1:(P==2)?n2:n3;
    cP = nP;
    nP = gq;

    const float g0 = comp<(P    ) & 3>(c0);
    const float g1 = comp<(P + 3) & 3>(c1);
    const float g2 = comp<(P + 2) & 3>(c2);
    const float g3 = comp<(P + 1) & 3>(c3);
    const float e0 = g0 * (w10 + pd1 + pd2);
    const float e1 = g1 * (w11 + w10 + w20);
    const float e2 = g2 * (w12 + w11 + w21);
    const float e3 = g3 * (w13 + w12 + w22);
    w20 = e0; w21 = e1; w22 = e2; w23 = e3;

    const float nx = __shfl_up(e3, 1);
    pd2 = pd1;
    pd1 = (t == 0) ? 0.0f : nx;

    // prefetch the LDS quad for step kk+2 (phase (P+2)&3)
    RQ = lds_rd<(P + 2) & 3>(lds4, kk + 2, rr0,rr1,rr2,rr3,
                             AA0,AA1,AA2,AA3, qq0,qq1,qq2,qq3);
}

__global__ __launch_bounds__(64, 1) void dp_softmin_wave(const float* __restrict__ C,
                                                         float* __restrict__ out) {
    const int b = blockIdx.x;
    const int t = threadIdx.x;
    const float* Cb = C + ((size_t)b << 16);
    const int t4 = 4 * t;

    __shared__ float4 lds4[4096];   // 64 KB

    // per-phase lane consts (read side)
    int rr0, rr1, rr2, rr3, AA0, AA1, AA2, AA3, qq0, qq1, qq2, qq3;
    {
        int r, g, q, qp;
        r = t4 + 0; g = r >> 4; q = r & 15; qp = q ^ (q >> 3);
        rr0 = r; AA0 = g * 64 + qp * 4; qq0 = ((q >> 1) & 3) ^ (g & 3);
        r = t4 + 1; g = r >> 4; q = r & 15; qp = q ^ (q >> 3);
        rr1 = r; AA1 = g * 64 + qp * 4; qq1 = ((q >> 1) & 3) ^ (g & 3);
        r = t4 + 2; g = r >> 4; q = r & 15; qp = q ^ (q >> 3);
        rr2 = r; AA2 = g * 64 + qp * 4; qq2 = ((q >> 1) & 3) ^ (g & 3);
        r = t4 + 3; g = r >> 4; q = r & 15; qp = q ^ (q >> 3);
        rr3 = r; AA3 = g * 64 + qp * 4; qq3 = ((q >> 1) & 3) ^ (g & 3);
    }
    // write-side lane consts (global gather permutation)
    const int qW  = (t >> 2) ^ (t >> 5);
    const int mmb = (t & 3) ^ ((qW >> 1) & 3);
    const int voff0 = 256 * qW + 4 * (mmb ^ 0);
    const int voff1 = 256 * qW + 4 * (mmb ^ 1);
    const int voff2 = 256 * qW + 4 * (mmb ^ 2);
    const int voff3 = 256 * qW + 4 * (mmb ^ 3);

    // c/n init: direct global loads (identical semantics to round 12)
    auto cl = [](int c) { return c < 0 ? 0 : (c > 252 ? 252 : c); };
    auto q4 = [&](int rb, int col) { return *(const float4*)(Cb + rb + col); };
    const int rb0 = (t4 + 0) << 8, rb1 = (t4 + 1) << 8,
              rb2 = (t4 + 2) << 8, rb3 = (t4 + 3) << 8;
    float4 c0 = g4f(q4(rb0, 0)), c1 = g4f(q4(rb1, 0)),
           c2 = g4f(q4(rb2, 0)), c3 = g4f(q4(rb3, 0));
    float4 n0 = g4f(q4(rb0, cl(4 - t4)));
    float4 n1 = c1, n2 = c2, n3 = c3;

    float wa0 = 0.0f, wa1 = 0.0f, wa2 = 0.0f, wa3 = 0.0f;
    float wb0 = 0.0f, wb1 = 0.0f, wb2 = 0.0f, wb3 = 0.0f;
    float pd1 = 0.0f, pd2 = 0.0f;
    int sig = 0;
    if (t == 0) wa0 = c0.x;          // seed: w(0,0) = g(0,0), diag 0 in set A

    // ---- prologue staging: (0,0),(1,0),(0,1) upfront; L0=(0,2), L1=(1,1)
    float4 P00 = *(const float4*)(Cb + 0    + voff0);
    float4 P10 = *(const float4*)(Cb + 4096 + voff1);
    float4 P01 = *(const float4*)(Cb + 16   + voff0);
    lds4[   0 + t] = P00;
    lds4[  64 + t] = P10;
    lds4[1024 + t] = P01;
    float4 RQ0, RQ1;
    RQ1 = lds_rd<1>(lds4, 1, rr0,rr1,rr2,rr3, AA0,AA1,AA2,AA3, qq0,qq1,qq2,qq3);
    RQ0 = lds_rd<2>(lds4, 2, rr0,rr1,rr2,rr3, AA0,AA1,AA2,AA3, qq0,qq1,qq2,qq3);

#define VOFFS voff0, voff1, voff2, voff3
#define CONSTS rr0,rr1,rr2,rr3, AA0,AA1,AA2,AA3, qq0,qq1,qq2,qq3
#define STEP_AB(kk, P, RQx) stepf<P>(kk, t, lds4, CONSTS, RQx, c0,c1,c2,c3, n0,n1,n2,n3, \
        wa0,wa1,wa2,wa3, wb0,wb1,wb2,wb3, pd1, pd2)
#define STEP_BA(kk, P, RQx) stepf<P>(kk, t, lds4, CONSTS, RQx, c0,c1,c2,c3, n0,n1,n2,n3, \
        wb0,wb1,wb2,wb3, wa0,wa1,wa2,wa3, pd1, pd2)

    // ---- prologue steps kk = 1..15 (sigma = 2; invalid stage_* fold away)
    {
        float4 L0, L1, L2, L3, L4, L5, L6, L7, L8, L9, L10, L11, L12, L13, L14, L15;
        stage_load<0>(2, Cb, VOFFS, L0);   // (0,2)
        stage_load<1>(2, Cb, VOFFS, L1);   // (1,1)
        stage_load<2>(2, Cb, VOFFS, L2);  stage_load<3>(2, Cb, VOFFS, L3);
        STEP_AB(1, 1, RQ1);
        stage_load<4>(2, Cb, VOFFS, L4);  stage_load<5>(2, Cb, VOFFS, L5);
        STEP_BA(2, 2, RQ0);
        stage_load<6>(2, Cb, VOFFS, L6);  stage_load<7>(2, Cb, VOFFS, L7);
        STEP_AB(3, 3, RQ1);
        stage_load<8>(2, Cb, VOFFS, L8);  stage_load<9>(2, Cb, VOFFS, L9);
        stage_write<0>(2, lds4, t, L0);   stage_write<1>(2, lds4, t, L1);
        STEP_BA(4, 0, RQ0);
        stage_load<10>(2, Cb, VOFFS, L10); stage_load<11>(2, Cb, VOFFS, L11);
        stage_write<2>(2, lds4, t, L2);   stage_write<3>(2, lds4, t, L3);
        STEP_AB(5, 1, RQ1);
        stage_load<12>(2, Cb, VOFFS, L12); stage_load<13>(2, Cb, VOFFS, L13);
        stage_write<4>(2, lds4, t, L4);   stage_write<5>(2, lds4, t, L5);
        STEP_BA(6, 2, RQ0);
        stage_load<14>(2, Cb, VOFFS, L14); stage_load<15>(2, Cb, VOFFS, L15);
        stage_write<6>(2, lds4, t, L6);   stage_write<7>(2, lds4, t, L7);
        STEP_AB(7, 3, RQ1);
        stage_write<8>(2, lds4, t, L8);   stage_write<9>(2, lds4, t, L9);
        STEP_BA(8, 0, RQ0);
        stage_write<10>(2, lds4, t, L10); stage_write<11>(2, lds4, t, L11);
        STEP_AB(9, 1, RQ1);
        stage_write<12>(2, lds4, t, L12); stage_write<13>(2, lds4, t, L13);
        STEP_BA(10, 2, RQ0);
        stage_write<14>(2, lds4, t, L14); stage_write<15>(2, lds4, t, L15);
        STEP_AB(11, 3, RQ1);
        STEP_BA(12, 0, RQ0);
        STEP_AB(13, 1, RQ1);
        STEP_BA(14, 2, RQ0);
        STEP_AB(15, 3, RQ1);
    }

    // ---- main loop kk = 16..495
#pragma clang loop unroll(disable)
    for (int kb = 16; kb <= 480; kb += 16) {
        if ((kb & 63) == 0) {
            // block-floating renorm: exact power-of-2, sig -= e
            float M = fmaxf(fmaxf(fmaxf(wa0, wa1), fmaxf(wa2, wa3)),
                            fmaxf(fmaxf(wb0, wb1), fmaxf(wb2, wb3)));
            #pragma unroll
            for (int m = 1; m < 64; m <<= 1) M = fmaxf(M, __shfl_xor(M, m));
            int e = ((__float_as_int(M) >> 23) & 255) - 127;
            float f = __int_as_float((127 - e) << 23);
            wa0 *= f; wa1 *= f; wa2 *= f; wa3 *= f;
            wb0 *= f; wb1 *= f; wb2 *= f; wb3 *= f;
            pd1 *= f; pd2 *= f;
            sig -= e;
        }
        const int sigma = (kb >> 4) + 2;
        float4 L0, L1, L2, L3, L4, L5, L6, L7, L8, L9, L10, L11, L12, L13, L14, L15;
        stage_load<0>(sigma, Cb, VOFFS, L0);  stage_load<1>(sigma, Cb, VOFFS, L1);
        STEP_BA(kb + 0, 0, RQ0);
        stage_load<2>(sigma, Cb, VOFFS, L2);  stage_load<3>(sigma, Cb, VOFFS, L3);
        STEP_AB(kb + 1, 1, RQ1);
        stage_load<4>(sigma, Cb, VOFFS, L4);  stage_load<5>(sigma, Cb, VOFFS, L5);
        STEP_BA(kb + 2, 2, RQ0);
        stage_load<6>(sigma, Cb, VOFFS, L6);  stage_load<7>(sigma, Cb, VOFFS, L7);
        STEP_AB(kb + 3, 3, RQ1);
        stage_load<8>(sigma, Cb, VOFFS, L8);  stage_load<9>(sigma, Cb, VOFFS, L9);
        stage_write<0>(sigma, lds4, t, L0);   stage_write<1>(sigma, lds4, t, L1);
        STEP_BA(kb + 4, 0, RQ0);
        stage_load<10>(sigma, Cb, VOFFS, L10); stage_load<11>(sigma, Cb, VOFFS, L11);
        stage_write<2>(sigma, lds4, t, L2);   stage_write<3>(sigma, lds4, t, L3);
        STEP_AB(kb + 5, 1, RQ1);
        stage_load<12>(sigma, Cb, VOFFS, L12); stage_load<13>(sigma, Cb, VOFFS, L13);
        stage_write<4>(sigma, lds4, t, L4);   stage_write<5>(sigma, lds4, t, L5);
        STEP_BA(kb + 6, 2, RQ0);
        stage_load<14>(sigma, Cb, VOFFS, L14); stage_load<15>(sigma, Cb, VOFFS, L15);
        stage_write<6>(sigma, lds4, t, L6);   stage_write<7>(sigma, lds4, t, L7);
        STEP_AB(kb + 7, 3, RQ1);
        stage_write<8>(sigma, lds4, t, L8);   stage_write<9>(sigma, lds4, t, L9);
        STEP_BA(kb + 8, 0, RQ0);
        stage_write<10>(sigma, lds4, t, L10); stage_write<11>(sigma, lds4, t, L11);
        STEP_AB(kb + 9, 1, RQ1);
        stage_write<12>(sigma, lds4, t, L12); stage_write<13>(sigma, lds4, t, L13);
        STEP_BA(kb + 10, 2, RQ0);
        stage_write<14>(sigma, lds4, t, L14); stage_write<15>(sigma, lds4, t, L15);
        STEP_AB(kb + 11, 3, RQ1);
        STEP_BA(kb + 12, 0, RQ0);
        STEP_AB(kb + 13, 1, RQ1);
        STEP_BA(kb + 14, 2, RQ0);
        STEP_AB(kb + 15, 3, RQ1);
    }

    // ---- epilogue kk = 496..510 (no staging: all windows already loaded)
    STEP_BA(496, 0, RQ0); STEP_AB(497, 1, RQ1); STEP_BA(498, 2, RQ0); STEP_AB(499, 3, RQ1);
    STEP_BA(500, 0, RQ0); STEP_AB(501, 1, RQ1); STEP_BA(502, 2, RQ0); STEP_AB(503, 3, RQ1);
    STEP_BA(504, 0, RQ0); STEP_AB(505, 1, RQ1); STEP_BA(506, 2, RQ0); STEP_AB(507, 3, RQ1);
    STEP_BA(508, 0, RQ0); STEP_AB(509, 1, RQ1); STEP_BA(510, 2, RQ0);

#undef STEP_AB
#undef STEP_BA
#undef VOFFS
#undef CONSTS

    // corner cell (255,255): lane 63, diag 510 (even) lands in set A slot 3
    if (t == 63) out[b] = ((float)sig - LOG2F(wa3)) * LN2;
}

extern "C" void kernel_launch(void* const* d_in, const int* in_sizes, int n_in,
                              void* d_out, int out_size, void* d_ws, size_t ws_size,
                              hipStream_t stream) {
    const float* C = (const float*)d_in[0];
    float* out = (float*)d_out;
    dp_softmin_wave<<<512, 64, 0, stream>>>(C, out);
}